// Round 5
// baseline (1040.997 us; speedup 1.0000x reference)
//
#include <hip/hip_runtime.h>
#include <stdint.h>
#include <math.h>

#define SEQ 2048
#define NH 16
#define DM 1024

typedef __bf16 bf16x8 __attribute__((ext_vector_type(8)));
typedef __bf16 bf16x2 __attribute__((ext_vector_type(2)));
typedef short s16x4 __attribute__((ext_vector_type(4)));
typedef short s16x8 __attribute__((ext_vector_type(8)));
typedef float f32x4 __attribute__((ext_vector_type(4)));
typedef float f32x2 __attribute__((ext_vector_type(2)));

#define ASM_VMCNT0  asm volatile("s_waitcnt vmcnt(0)" ::: "memory")
#define ASM_BARRIER asm volatile("s_barrier" ::: "memory")

__device__ __forceinline__ unsigned short f2bf(float f) {
  union { float f; unsigned u; } v; v.f = f;
  unsigned r = v.u + 0x7fffu + ((v.u >> 16) & 1u);
  return (unsigned short)(r >> 16);
}
__device__ __forceinline__ unsigned pk2(float a, float b) {
  f32x2 v = {a, b};
  bf16x2 r = __builtin_convertvector(v, bf16x2);  // v_cvt_pk_bf16_f32
  union { bf16x2 h; unsigned u; } c; c.h = r;
  return c.u;
}
__device__ __forceinline__ void load_lds16(const void* g, void* l) {
  __builtin_amdgcn_global_load_lds((__attribute__((address_space(1))) void*)g,
                                   (__attribute__((address_space(3))) void*)l,
                                   16, 0, 0);
}

// ---------------------------------------------------------------------------
// fp32 -> bf16 conversion: x (4M) + wq/wk/wv/wo (1M each) into ws.
// ---------------------------------------------------------------------------
__global__ void cvt_all(const float* __restrict__ x, const float* __restrict__ wq,
                        const float* __restrict__ wk, const float* __restrict__ wv,
                        const float* __restrict__ wo, unsigned short* __restrict__ ws) {
  const int i = blockIdx.x * blockDim.x + threadIdx.x;
  const int off = i * 4;
  const float* src;
  unsigned short* dst;
  if (off < 4194304) {
    src = x + off;  dst = ws + off;
  } else {
    const int r = off - 4194304;
    const int w = r >> 20, o = r & 1048575;
    const float* tabs[4] = {wq, wk, wv, wo};
    src = tabs[w] + o;  dst = ws + 4194304 + (w << 20) + o;
  }
  const float4 v = *(const float4*)src;
  uint2 u;
  u.x = pk2(v.x, v.y);
  u.y = pk2(v.z, v.w);
  *(uint2*)dst = u;
}

// ---------------------------------------------------------------------------
// Fused QKV projection: C = x (4096x1024) @ W3^T (W3 = [wq;wk;wv], 3072x1024).
// 128x128 tiles, grid (24,32) = 768 blocks; 3 blocks/CU.
// V epilogue writes the key dim PERMUTED within each 64-block:
//   key = nb*16 + quad*4 + j  ->  g = quad*16 + (nb>>1)*8 + (nb&1)*4 + j
// so flash PV A-fragments (4 keys/lane, 2 nb per 16B) are b128-loadable.
// ---------------------------------------------------------------------------
__launch_bounds__(256, 3)
__global__ void gemm_qkv(const unsigned short* __restrict__ X,
                         const unsigned short* __restrict__ W3,
                         unsigned short* __restrict__ Qr,
                         unsigned short* __restrict__ Kr,
                         unsigned short* __restrict__ Vt,
                         const int* __restrict__ tp) {
  __shared__ __align__(16) char smem[32768];

  const int t = threadIdx.x;
  const int lane = t & 63, wave = t >> 6;
  const int quad = lane >> 4, l16 = lane & 15;
  const int m0 = blockIdx.y * 128, n0 = blockIdx.x * 128;
  const int wm = (wave >> 1) * 64, wn = (wave & 1) * 64;

  f32x4 acc[4][4];
#pragma unroll
  for (int i = 0; i < 4; i++)
#pragma unroll
    for (int j = 0; j < 4; j++) { acc[i][j][0]=0.f; acc[i][j][1]=0.f; acc[i][j][2]=0.f; acc[i][j][3]=0.f; }

  const int rr = t >> 2;
  const int cc = (t & 3) * 8;

#define QKV_STAGE(bufidx, k0_) do {                                               \
    char* a_ = smem + (bufidx) * 8192;                                            \
    char* b_ = smem + 16384 + (bufidx) * 8192;                                    \
    _Pragma("unroll")                                                             \
    for (int i_ = 0; i_ < 2; i_++) {                                              \
      load_lds16(X  + (uint64_t)(m0 + i_ * 64 + rr) * 1024 + (k0_) + cc,          \
                 a_ + i_ * 4096 + wave * 1024);                                   \
      load_lds16(W3 + (uint64_t)(n0 + i_ * 64 + rr) * 1024 + (k0_) + cc,          \
                 b_ + i_ * 4096 + wave * 1024);                                   \
    }                                                                             \
  } while (0)

  QKV_STAGE(0, 0);

  for (int k0 = 0; k0 < 1024; k0 += 32) {
    const int buf = (k0 >> 5) & 1;
    ASM_VMCNT0;
    ASM_BARRIER;
    if (k0 + 32 < 1024) QKV_STAGE(buf ^ 1, k0 + 32);
    char* As = smem + buf * 8192;
    char* Bs = smem + 16384 + buf * 8192;

    bf16x8 af[4], bfr[4];
#pragma unroll
    for (int i = 0; i < 4; i++) {
      af[i]  = *(const bf16x8*)(As + (wm + i * 16 + l16) * 64 + quad * 16);
      bfr[i] = *(const bf16x8*)(Bs + (wn + i * 16 + l16) * 64 + quad * 16);
    }
#pragma unroll
    for (int i = 0; i < 4; i++)
#pragma unroll
      for (int j = 0; j < 4; j++)
        acc[i][j] = __builtin_amdgcn_mfma_f32_16x16x32_bf16(af[i], bfr[j], acc[i][j], 0, 0, 0);
  }
#undef QKV_STAGE

  if (n0 < 2048) {
    unsigned short* dst = (n0 < 1024) ? Qr : Kr;
    float fr[4]; int dd[4], hh[4];
#pragma unroll
    for (int j = 0; j < 4; j++) {
      const int n = n0 + wn + j * 16 + l16;
      dd[j] = n & 63;
      hh[j] = (n & 1023) >> 6;
      fr[j] = __builtin_amdgcn_exp2f(-0.20762050594f * (float)(dd[j] & ~1)) * 0.15915494309f;
    }
    const float sgnodd = (l16 & 1) ? 1.f : -1.f;
#pragma unroll
    for (int i = 0; i < 4; i++) {
#pragma unroll
      for (int r = 0; r < 4; r++) {
        const int m = m0 + wm + i * 16 + quad * 4 + r;
        const int s = m & 2047, b = m >> 11;
        const float posf = (float)tp[m];
#pragma unroll
        for (int j = 0; j < 4; j++) {
          const float v = acc[i][j][r];
          const float p = __shfl_xor(v, 1);
          float rev = posf * fr[j];
          rev -= floorf(rev);
          float sn, cs;
          asm("v_sin_f32 %0, %1" : "=v"(sn) : "v"(rev));
          asm("v_cos_f32 %0, %1" : "=v"(cs) : "v"(rev));
          const float rv = fmaf(v, cs, p * sn * sgnodd);
          dst[((uint64_t)((b * NH + hh[j]) * SEQ + s)) * 64 + dd[j]] = f2bf(rv);
        }
      }
    }
  } else {
    // V -> Vt (b,h,d,s_permuted): 4 consecutive s (=j) share (quad_v, nb_v).
#pragma unroll
    for (int i = 0; i < 4; i++) {
      const int m = m0 + wm + i * 16 + quad * 4;
      const int s = m & 2047, b = m >> 11;
      const int sl = s & 63;
      const int qv = (sl >> 2) & 3, nv = sl >> 4;
      const int g = (s & ~63) + qv * 16 + (nv >> 1) * 8 + (nv & 1) * 4;
#pragma unroll
      for (int j = 0; j < 4; j++) {
        const int n = n0 - 2048 + wn + j * 16 + l16;
        const int h = n >> 6, d = n & 63;
        uint2 w;
        w.x = pk2(acc[i][j][0], acc[i][j][1]);
        w.y = pk2(acc[i][j][2], acc[i][j][3]);
        *(uint2*)(Vt + ((uint64_t)((b * NH + h) * 64 + d)) * SEQ + g) = w;
      }
    }
  }
}

// ---------------------------------------------------------------------------
// Output projection: C = At (4096x1024) @ wo^T, fp32 out. 128x128 tiles,
// grid (8,32) = 256 blocks (1/CU, uniform). 2x MFMA per staged byte vs 128x64.
// ---------------------------------------------------------------------------
__launch_bounds__(256, 2)
__global__ void gemm_ao(const unsigned short* __restrict__ A,
                        const unsigned short* __restrict__ B,
                        float* __restrict__ C) {
  __shared__ __align__(16) char smem[32768];

  const int t = threadIdx.x;
  const int lane = t & 63, wave = t >> 6;
  const int quad = lane >> 4, l16 = lane & 15;
  const int m0 = blockIdx.y * 128, n0 = blockIdx.x * 128;
  const int wm = (wave >> 1) * 64, wn = (wave & 1) * 64;

  f32x4 acc[4][4];
#pragma unroll
  for (int i = 0; i < 4; i++)
#pragma unroll
    for (int j = 0; j < 4; j++) { acc[i][j][0]=0.f; acc[i][j][1]=0.f; acc[i][j][2]=0.f; acc[i][j][3]=0.f; }

  const int rr = t >> 2;
  const int cc = (t & 3) * 8;

#define AO_STAGE(bufidx, k0_) do {                                               \
    char* a_ = smem + (bufidx) * 8192;                                            \
    char* b_ = smem + 16384 + (bufidx) * 8192;                                    \
    _Pragma("unroll")                                                             \
    for (int i_ = 0; i_ < 2; i_++) {                                              \
      load_lds16(A + (uint64_t)(m0 + i_ * 64 + rr) * 1024 + (k0_) + cc,           \
                 a_ + i_ * 4096 + wave * 1024);                                   \
      load_lds16(B + (uint64_t)(n0 + i_ * 64 + rr) * 1024 + (k0_) + cc,           \
                 b_ + i_ * 4096 + wave * 1024);                                   \
    }                                                                             \
  } while (0)

  AO_STAGE(0, 0);

  for (int k0 = 0; k0 < 1024; k0 += 32) {
    const int buf = (k0 >> 5) & 1;
    ASM_VMCNT0;
    ASM_BARRIER;
    if (k0 + 32 < 1024) AO_STAGE(buf ^ 1, k0 + 32);
    char* As = smem + buf * 8192;
    char* Bs = smem + 16384 + buf * 8192;

    bf16x8 af[4], bfr[4];
#pragma unroll
    for (int i = 0; i < 4; i++) {
      af[i]  = *(const bf16x8*)(As + (wm + i * 16 + l16) * 64 + quad * 16);
      bfr[i] = *(const bf16x8*)(Bs + (wn + i * 16 + l16) * 64 + quad * 16);
    }
#pragma unroll
    for (int i = 0; i < 4; i++)
#pragma unroll
      for (int j = 0; j < 4; j++)
        acc[i][j] = __builtin_amdgcn_mfma_f32_16x16x32_bf16(af[i], bfr[j], acc[i][j], 0, 0, 0);
  }
#undef AO_STAGE

#pragma unroll
  for (int i = 0; i < 4; i++)
#pragma unroll
    for (int j = 0; j < 4; j++)
#pragma unroll
      for (int r = 0; r < 4; r++) {
        const int m = m0 + wm + i * 16 + quad * 4 + r;
        const int n = n0 + wn + j * 16 + l16;
        C[(uint64_t)m * DM + n] = acc[i][j][r];
      }
}

// ---------------------------------------------------------------------------
// Flash attention r14: 128-row Q-tiles + uniform split-K.
// R4 post-mortem: t_iter ~= 2.3us/iter at ~340cy of issue/wave; largest
// component is LDS reads (each wave reads the FULL 8KB K + 8KB V tile ->
// 64KB/block-iter, 256KB/CU/t_iter ~= 2048cy at 128B/cy). Fix: Q-tile = 128
// rows, 4 waves x 32 q-rows (two independent 16-q subgroups per wave, R2's
// validated inner) -> each staged K/V tile serves 2 units: LDS reads, staging
// and barriers PER UNIT halve; per-wave ILP doubles (8 indep chains/SIMD).
// R2's regression causes (2 blocks/CU, 18-32-unit imbalance) are fixed by
// R4's machinery: per bh, pair tiles (t,15-t) = 34 units, cut at K-tile
// granularity into 4 blocks of {9,9,8,8} units -> 1024 uniform blocks, 4/CU,
// 32KB LDS. All tiles finalize via combine: flash always writes unnormalized
// f32 O + row-sums l to slot (bh, pair, block, small/big); combine sums the
// 1-4 partials per tile and normalizes. u%8==bh%8 keeps a bh on one XCD.
// ---------------------------------------------------------------------------
__launch_bounds__(256, 4)
__global__ void flash_attn(const unsigned short* __restrict__ Q,
                           const unsigned short* __restrict__ K,
                           const unsigned short* __restrict__ Vt,
                           float* __restrict__ Pt) {
  __shared__ __align__(16) char smem[32768];
  // K dbuf: 0 / 8192; V dbuf: 16384 / 24576

  const int t = threadIdx.x;
  const int lane = t & 63, wid = t >> 6;     // wid = 0..3
  const int quad = lane >> 4, l16 = lane & 15;
  const int u = blockIdx.x;
  const int bh = u & 31;
  const int tt = (u >> 5) & 7;               // pair index: tiles (tt, 15-tt)
  const int j = u >> 8;                      // slice 0..3 of the 34-unit pair
  const uint64_t base = (uint64_t)bh * (SEQ * 64);

  const int smallU = 2 * tt + 2;             // units of small tile tt
  const int s = (j == 0) ? 0 : (j == 1) ? 9 : (j == 2) ? 18 : 26;
  const int e = (j == 0) ? 9 : (j == 1) ? 18 : (j == 2) ? 26 : 34;

  int qb = (s < smallU) ? tt * 128 : (15 - tt) * 128;
  int qlo = qb + wid * 32;                   // wave's 32-row range start

  // Q B-fragments, 2 subgroups (n=q=l16, k=d=kk*32+quad*8+jj)
  bf16x8 qf[2][2];
  {
    const unsigned short* qp0 = Q + base + (uint64_t)(qlo + l16) * 64 + quad * 8;
    qf[0][0] = *(const bf16x8*)qp0;  qf[0][1] = *(const bf16x8*)(qp0 + 32);
    const unsigned short* qp1 = Q + base + (uint64_t)(qlo + 16 + l16) * 64 + quad * 8;
    qf[1][0] = *(const bf16x8*)qp1;  qf[1][1] = *(const bf16x8*)(qp1 + 32);
  }

  f32x4 o0[4], o1[4];
#pragma unroll
  for (int i = 0; i < 4; i++) {
    o0[i][0]=0.f; o0[i][1]=0.f; o0[i][2]=0.f; o0[i][3]=0.f;
    o1[i][0]=0.f; o1[i][1]=0.f; o1[i][2]=0.f; o1[i][3]=0.f;
  }
  float lI0 = 0.f, lI1 = 0.f;

  // staging: 256 threads cover a 64-row x 128B tile in 2 calls/array.
  // LDS chunk c at row r holds global 16B-chunk c ^ (r&7).
  const int sr8 = lane >> 3;
  const int sc = ((lane & 7) ^ sr8) * 8;     // shorts
  const int swz = (l16 & 7);

#define STAGE(bufidx, kb_) do {                                                   \
    _Pragma("unroll")                                                             \
    for (int i_ = 0; i_ < 2; i_++) {                                              \
      const int r_ = wid * 16 + i_ * 8 + sr8;                                     \
      load_lds16(K  + base + (uint64_t)((kb_) + r_) * 64 + sc,                    \
                 smem + (bufidx) * 8192 + wid * 2048 + i_ * 1024);                \
      load_lds16(Vt + base + (uint64_t)r_ * SEQ + (kb_) + sc,                     \
                 smem + 16384 + (bufidx) * 8192 + wid * 2048 + i_ * 1024);        \
    }                                                                             \
  } while (0)

  // K-tile base for unit i of the pair sequence (K/V are tile-agnostic).
#define KB_OF(i_) ((((i_) < smallU) ? (i_) : (i_) - smallU) * 64)

#define WRITE_PARTIAL(curflag_) do {                                              \
    float lr0 = lI0; lr0 += __shfl_xor(lr0, 16); lr0 += __shfl_xor(lr0, 32);      \
    float lr1 = lI1; lr1 += __shfl_xor(lr1, 16); lr1 += __shfl_xor(lr1, 32);      \
    float* Pp = Pt + (uint64_t)(((bh * 8 + tt) * 4 + j) * 2 + (curflag_)) * 8320; \
    const int row0 = wid * 32 + l16, row1 = row0 + 16;                            \
    _Pragma("unroll")                                                             \
    for (int db = 0; db < 4; db++) {                                              \
      *(f32x4*)(Pp + row0 * 64 + db * 16 + quad * 4) = o0[db];                    \
      *(f32x4*)(Pp + row1 * 64 + db * 16 + quad * 4) = o1[db];                    \
    }                                                                             \
    if (quad == 0) { Pp[8192 + row0] = lr0; Pp[8192 + row1] = lr1; }              \
  } while (0)

  STAGE(0, KB_OF(s));

  const float c1 = 0.18033688011f;  // log2(e)/8

  for (int it = s; it < e; it++) {
    const int kb = KB_OF(it);
    const int buf = (it - s) & 1;
    ASM_VMCNT0;     // stage(it) loads were issued a full iteration ago
    ASM_BARRIER;
    if (it + 1 < e) STAGE(buf ^ 1, KB_OF(it + 1));
    char* ks = smem + buf * 8192;
    char* vs = smem + 16384 + buf * 8192;

    int nbmax = ((qlo + 31 - kb) >> 4) + 1;
    nbmax = nbmax > 4 ? 4 : (nbmax < 0 ? 0 : nbmax);
    const bool diag = (kb + 63) > qlo;       // wave-uniform
    const int qg0 = qlo + l16, qg1 = qlo + 16 + l16;

    // S^T = K Q^T : key = kb + nb*16 + quad*4 + r, q = l16 (per subgroup)
    f32x4 sf0[4], sf1[4];
    float ls0 = 0.f, ls1 = 0.f;
#pragma unroll
    for (int nb = 0; nb < 4; nb++) {
      if (nb < nbmax) {
        f32x4 s0; s0[0]=0.f; s0[1]=0.f; s0[2]=0.f; s0[3]=0.f;
        f32x4 s1; s1[0]=0.f; s1[1]=0.f; s1[2]=0.f; s1[3]=0.f;
#pragma unroll
        for (int kk = 0; kk < 2; kk++) {
          bf16x8 kfr = *(const bf16x8*)(ks + (nb * 16 + l16) * 128 + (((kk * 4 + quad) ^ swz) * 16));
          s0 = __builtin_amdgcn_mfma_f32_16x16x32_bf16(kfr, qf[0][kk], s0, 0, 0, 0);
          s1 = __builtin_amdgcn_mfma_f32_16x16x32_bf16(kfr, qf[1][kk], s1, 0, 0, 0);
        }
        if (diag) {
#pragma unroll
          for (int r = 0; r < 4; r++) {
            const int key = kb + nb * 16 + quad * 4 + r;
            const float p0 = (key <= qg0) ? __builtin_amdgcn_exp2f(s0[r] * c1) : 0.f;
            sf0[nb][r] = p0;  ls0 += p0;
            const float p1 = (key <= qg1) ? __builtin_amdgcn_exp2f(s1[r] * c1) : 0.f;
            sf1[nb][r] = p1;  ls1 += p1;
          }
        } else {
#pragma unroll
          for (int r = 0; r < 4; r++) {
            const float p0 = __builtin_amdgcn_exp2f(s0[r] * c1);
            sf0[nb][r] = p0;  ls0 += p0;
            const float p1 = __builtin_amdgcn_exp2f(s1[r] * c1);
            sf1[nb][r] = p1;  ls1 += p1;
          }
        }
      }
    }
    lI0 += ls0;  lI1 += ls1;

    // PV: P in regs; V-frag pair (nb=2np, 2np+1) in ONE b128 from permuted V
    // layout; each V fragment feeds BOTH subgroups (4 MFMA per read).
#pragma unroll
    for (int np = 0; np < 2; np++) {
      if (2 * np < nbmax) {
        union { uint2 u; s16x4 h; } a0, b0, a1, b1;
        a0.u.x = pk2(sf0[2 * np][0], sf0[2 * np][1]);
        a0.u.y = pk2(sf0[2 * np][2], sf0[2 * np][3]);
        b0.u.x = pk2(sf1[2 * np][0], sf1[2 * np][1]);
        b0.u.y = pk2(sf1[2 * np][2], sf1[2 * np][3]);
        const bool hi = (2 * np + 1 < nbmax);
        if (hi) {
          a1.u.x = pk2(sf0[2 * np + 1][0], sf0[2 * np + 1][1]);
          a1.u.y = pk2(sf0[2 * np + 1][2], sf0[2 * np + 1][3]);
          b1.u.x = pk2(sf1[2 * np + 1][0], sf1[2 * np + 1][1]);
          b1.u.y = pk2(sf1[2 * np + 1][2], sf1[2 * np + 1][3]);
        }
#pragma unroll
        for (int db = 0; db < 4; db++) {
          s16x8 vv = *(const s16x8*)(vs + (db * 16 + l16) * 128 +
                                     (((quad * 2 + np) ^ swz) * 16));
          s16x4 vlo = __builtin_shufflevector(vv, vv, 0, 1, 2, 3);
          o0[db] = __builtin_amdgcn_mfma_f32_16x16x16bf16_1k(vlo, a0.h, o0[db], 0, 0, 0);
          o1[db] = __builtin_amdgcn_mfma_f32_16x16x16bf16_1k(vlo, b0.h, o1[db], 0, 0, 0);
          if (hi) {
            s16x4 vhi = __builtin_shufflevector(vv, vv, 4, 5, 6, 7);
            o0[db] = __builtin_amdgcn_mfma_f32_16x16x16bf16_1k(vhi, a1.h, o0[db], 0, 0, 0);
            o1[db] = __builtin_amdgcn_mfma_f32_16x16x16bf16_1k(vhi, b1.h, o1[db], 0, 0, 0);
          }
        }
      }
    }

    // tile end: write partial; switch small -> big if the slice continues
    if ((it + 1 == e) || (it + 1 == smallU)) {
      WRITE_PARTIAL((it >= smallU) ? 1 : 0);
      if (it + 1 == smallU && it + 1 < e) {
#pragma unroll
        for (int i = 0; i < 4; i++) {
          o0[i][0]=0.f; o0[i][1]=0.f; o0[i][2]=0.f; o0[i][3]=0.f;
          o1[i][0]=0.f; o1[i][1]=0.f; o1[i][2]=0.f; o1[i][3]=0.f;
        }
        lI0 = 0.f;  lI1 = 0.f;
        qb = (15 - tt) * 128;
        qlo = qb + wid * 32;
        const unsigned short* qp0 = Q + base + (uint64_t)(qlo + l16) * 64 + quad * 8;
        qf[0][0] = *(const bf16x8*)qp0;  qf[0][1] = *(const bf16x8*)(qp0 + 32);
        const unsigned short* qp1 = Q + base + (uint64_t)(qlo + 16 + l16) * 64 + quad * 8;
        qf[1][0] = *(const bf16x8*)qp1;  qf[1][1] = *(const bf16x8*)(qp1 + 32);
      }
    }
  }
#undef STAGE
#undef KB_OF
#undef WRITE_PARTIAL
}

// ---------------------------------------------------------------------------
// Combine the 1-4 partials of each 128-row tile: O = sum O_j, l = sum l_j,
// out = bf16(O/l). Grid (16, 32) = one block per (tile tau, bh), 256 thr.
// Slot (bh, pair, block j, flag) exists iff block j's unit range [B[j],B[j+1])
// intersects the tile's range ([0,smallU) small / [smallU,34) big) -- the
// exact condition under which flash wrote it.
// ---------------------------------------------------------------------------
__global__ void flash_combine(const float* __restrict__ Pt,
                              unsigned short* __restrict__ Oa) {
  const int tau = blockIdx.x;                // 0..15
  const int bh = blockIdx.y;                 // 0..31
  const int tt = (tau <= 7) ? tau : 15 - tau;
  const int flag = (tau > 7) ? 1 : 0;
  const int smallU = 2 * tt + 2;
  const int lo = flag ? smallU : 0;
  const int hi = flag ? 34 : smallU;
  const int qb = tau * 128;
  const int b = bh >> 4, h = bh & 15;
  const int tid = threadIdx.x;
  const int r = tid >> 1, c0 = (tid & 1) * 32;
  const int Bnd[5] = {0, 9, 18, 26, 34};

  f32x4 acc[8];
#pragma unroll
  for (int k = 0; k < 8; k++) { acc[k][0]=0.f; acc[k][1]=0.f; acc[k][2]=0.f; acc[k][3]=0.f; }
  float l = 0.f;

#pragma unroll
  for (int j = 0; j < 4; j++) {
    const int a = (Bnd[j] > lo) ? Bnd[j] : lo;
    const int z = (Bnd[j + 1] < hi) ? Bnd[j + 1] : hi;
    if (a < z) {
      const float* Pp = Pt + (uint64_t)(((bh * 8 + tt) * 4 + j) * 2 + flag) * 8320;
      l += Pp[8192 + r];
#pragma unroll
      for (int k = 0; k < 8; k++) {
        const f32x4 v = *(const f32x4*)(Pp + r * 64 + c0 + k * 4);
        acc[k][0] += v[0]; acc[k][1] += v[1]; acc[k][2] += v[2]; acc[k][3] += v[3];
      }
    }
  }

  const float inv = 1.0f / l;
  unsigned short* orow = Oa + ((uint64_t)(b * SEQ + qb + r)) * DM + h * 64 + c0;
#pragma unroll
  for (int k = 0; k < 8; k++) {
    uint2 w;
    w.x = pk2(acc[k][0] * inv, acc[k][1] * inv);
    w.y = pk2(acc[k][2] * inv, acc[k][3] * inv);
    *(uint2*)(orow + k * 4) = w;
  }
}

extern "C" void kernel_launch(void* const* d_in, const int* in_sizes, int n_in,
                              void* d_out, int out_size, void* d_ws, size_t ws_size,
                              hipStream_t stream) {
  const float* x  = (const float*)d_in[0];
  const int* tp   = (const int*)d_in[1];
  const float* wq = (const float*)d_in[2];
  const float* wk = (const float*)d_in[3];
  const float* wv = (const float*)d_in[4];
  const float* wo = (const float*)d_in[5];
  float* out = (float*)d_out;

  unsigned short* ws = (unsigned short*)d_ws;
  unsigned short* xb  = ws;                   // (b,s,dm) bf16        8 MB
  unsigned short* w3b = ws + 4194304;         // [wq;wk;wv] 3072x1024 6 MB
  unsigned short* wob = ws + 7340032;         // 2 MB
  unsigned short* Qr  = ws + 8388608;         // (b,h,s,64)  8 MB
  unsigned short* Kr  = ws + 12582912;        // (b,h,s,64)  8 MB
  unsigned short* Vt  = ws + 16777216;        // (b,h,64,s-perm)  8 MB
  unsigned short* At  = ws + 20971520;        // (b,s,h*64)  8 MB
  float* Pt = (float*)(ws + 25165824);        // split-K partials 68 MB

  cvt_all<<<8192, 256, 0, stream>>>(x, wq, wk, wv, wo, ws);
  gemm_qkv<<<dim3(24, 32), 256, 0, stream>>>(xb, w3b, Qr, Kr, Vt, tp);
  flash_attn<<<1024, 256, 0, stream>>>(Qr, Kr, Vt, Pt);
  flash_combine<<<dim3(16, 32), 256, 0, stream>>>(Pt, At);
  gemm_ao<<<dim3(8, 32), 256, 0, stream>>>(At, wob, out);
}

// Round 6
// 173.745 us; speedup vs baseline: 5.9915x; 5.9915x over previous
//
#include <hip/hip_runtime.h>
#include <stdint.h>
#include <math.h>

#define SEQ 2048
#define NH 16
#define DM 1024

typedef __bf16 bf16x8 __attribute__((ext_vector_type(8)));
typedef __bf16 bf16x2 __attribute__((ext_vector_type(2)));
typedef short s16x4 __attribute__((ext_vector_type(4)));
typedef short s16x8 __attribute__((ext_vector_type(8)));
typedef float f32x4 __attribute__((ext_vector_type(4)));
typedef float f32x2 __attribute__((ext_vector_type(2)));

#define ASM_VMCNT0  asm volatile("s_waitcnt vmcnt(0)" ::: "memory")
#define ASM_BARRIER asm volatile("s_barrier" ::: "memory")

__device__ __forceinline__ unsigned short f2bf(float f) {
  union { float f; unsigned u; } v; v.f = f;
  unsigned r = v.u + 0x7fffu + ((v.u >> 16) & 1u);
  return (unsigned short)(r >> 16);
}
__device__ __forceinline__ unsigned pk2(float a, float b) {
  f32x2 v = {a, b};
  bf16x2 r = __builtin_convertvector(v, bf16x2);  // v_cvt_pk_bf16_f32
  union { bf16x2 h; unsigned u; } c; c.h = r;
  return c.u;
}
__device__ __forceinline__ void load_lds16(const void* g, void* l) {
  __builtin_amdgcn_global_load_lds((__attribute__((address_space(1))) void*)g,
                                   (__attribute__((address_space(3))) void*)l,
                                   16, 0, 0);
}

// ---------------------------------------------------------------------------
// fp32 -> bf16 conversion: x (4M) + wq/wk/wv/wo (1M each) into ws.
// ---------------------------------------------------------------------------
__global__ void cvt_all(const float* __restrict__ x, const float* __restrict__ wq,
                        const float* __restrict__ wk, const float* __restrict__ wv,
                        const float* __restrict__ wo, unsigned short* __restrict__ ws) {
  const int i = blockIdx.x * blockDim.x + threadIdx.x;
  const int off = i * 4;
  const float* src;
  unsigned short* dst;
  if (off < 4194304) {
    src = x + off;  dst = ws + off;
  } else {
    const int r = off - 4194304;
    const int w = r >> 20, o = r & 1048575;
    const float* tabs[4] = {wq, wk, wv, wo};
    src = tabs[w] + o;  dst = ws + 4194304 + (w << 20) + o;
  }
  const float4 v = *(const float4*)src;
  uint2 u;
  u.x = pk2(v.x, v.y);
  u.y = pk2(v.z, v.w);
  *(uint2*)dst = u;
}

// ---------------------------------------------------------------------------
// Fused QKV projection: C = x (4096x1024) @ W3^T (W3 = [wq;wk;wv], 3072x1024).
// 128x128 tiles, grid (24,32) = 768 blocks; 3 blocks/CU.
// V epilogue writes the key dim PERMUTED within each 64-block:
//   key = nb*16 + quad*4 + j  ->  g = quad*16 + (nb>>1)*8 + (nb&1)*4 + j
// so flash PV A-fragments (4 keys/lane, 2 nb per 16B) are b128-loadable.
// ---------------------------------------------------------------------------
__launch_bounds__(256, 3)
__global__ void gemm_qkv(const unsigned short* __restrict__ X,
                         const unsigned short* __restrict__ W3,
                         unsigned short* __restrict__ Qr,
                         unsigned short* __restrict__ Kr,
                         unsigned short* __restrict__ Vt,
                         const int* __restrict__ tp) {
  __shared__ __align__(16) char smem[32768];

  const int t = threadIdx.x;
  const int lane = t & 63, wave = t >> 6;
  const int quad = lane >> 4, l16 = lane & 15;
  const int m0 = blockIdx.y * 128, n0 = blockIdx.x * 128;
  const int wm = (wave >> 1) * 64, wn = (wave & 1) * 64;

  f32x4 acc[4][4];
#pragma unroll
  for (int i = 0; i < 4; i++)
#pragma unroll
    for (int j = 0; j < 4; j++) { acc[i][j][0]=0.f; acc[i][j][1]=0.f; acc[i][j][2]=0.f; acc[i][j][3]=0.f; }

  const int rr = t >> 2;
  const int cc = (t & 3) * 8;

#define QKV_STAGE(bufidx, k0_) do {                                               \
    char* a_ = smem + (bufidx) * 8192;                                            \
    char* b_ = smem + 16384 + (bufidx) * 8192;                                    \
    _Pragma("unroll")                                                             \
    for (int i_ = 0; i_ < 2; i_++) {                                              \
      load_lds16(X  + (uint64_t)(m0 + i_ * 64 + rr) * 1024 + (k0_) + cc,          \
                 a_ + i_ * 4096 + wave * 1024);                                   \
      load_lds16(W3 + (uint64_t)(n0 + i_ * 64 + rr) * 1024 + (k0_) + cc,          \
                 b_ + i_ * 4096 + wave * 1024);                                   \
    }                                                                             \
  } while (0)

  QKV_STAGE(0, 0);

  for (int k0 = 0; k0 < 1024; k0 += 32) {
    const int buf = (k0 >> 5) & 1;
    ASM_VMCNT0;
    ASM_BARRIER;
    if (k0 + 32 < 1024) QKV_STAGE(buf ^ 1, k0 + 32);
    char* As = smem + buf * 8192;
    char* Bs = smem + 16384 + buf * 8192;

    bf16x8 af[4], bfr[4];
#pragma unroll
    for (int i = 0; i < 4; i++) {
      af[i]  = *(const bf16x8*)(As + (wm + i * 16 + l16) * 64 + quad * 16);
      bfr[i] = *(const bf16x8*)(Bs + (wn + i * 16 + l16) * 64 + quad * 16);
    }
#pragma unroll
    for (int i = 0; i < 4; i++)
#pragma unroll
      for (int j = 0; j < 4; j++)
        acc[i][j] = __builtin_amdgcn_mfma_f32_16x16x32_bf16(af[i], bfr[j], acc[i][j], 0, 0, 0);
  }
#undef QKV_STAGE

  if (n0 < 2048) {
    unsigned short* dst = (n0 < 1024) ? Qr : Kr;
    float fr[4]; int dd[4], hh[4];
#pragma unroll
    for (int j = 0; j < 4; j++) {
      const int n = n0 + wn + j * 16 + l16;
      dd[j] = n & 63;
      hh[j] = (n & 1023) >> 6;
      fr[j] = __builtin_amdgcn_exp2f(-0.20762050594f * (float)(dd[j] & ~1)) * 0.15915494309f;
    }
    const float sgnodd = (l16 & 1) ? 1.f : -1.f;
#pragma unroll
    for (int i = 0; i < 4; i++) {
#pragma unroll
      for (int r = 0; r < 4; r++) {
        const int m = m0 + wm + i * 16 + quad * 4 + r;
        const int s = m & 2047, b = m >> 11;
        const float posf = (float)tp[m];
#pragma unroll
        for (int j = 0; j < 4; j++) {
          const float v = acc[i][j][r];
          const float p = __shfl_xor(v, 1);
          float rev = posf * fr[j];
          rev -= floorf(rev);
          float sn, cs;
          asm("v_sin_f32 %0, %1" : "=v"(sn) : "v"(rev));
          asm("v_cos_f32 %0, %1" : "=v"(cs) : "v"(rev));
          const float rv = fmaf(v, cs, p * sn * sgnodd);
          dst[((uint64_t)((b * NH + hh[j]) * SEQ + s)) * 64 + dd[j]] = f2bf(rv);
        }
      }
    }
  } else {
    // V -> Vt (b,h,d,s_permuted): 4 consecutive s (=j) share (quad_v, nb_v).
#pragma unroll
    for (int i = 0; i < 4; i++) {
      const int m = m0 + wm + i * 16 + quad * 4;
      const int s = m & 2047, b = m >> 11;
      const int sl = s & 63;
      const int qv = (sl >> 2) & 3, nv = sl >> 4;
      const int g = (s & ~63) + qv * 16 + (nv >> 1) * 8 + (nv & 1) * 4;
#pragma unroll
      for (int j = 0; j < 4; j++) {
        const int n = n0 - 2048 + wn + j * 16 + l16;
        const int h = n >> 6, d = n & 63;
        uint2 w;
        w.x = pk2(acc[i][j][0], acc[i][j][1]);
        w.y = pk2(acc[i][j][2], acc[i][j][3]);
        *(uint2*)(Vt + ((uint64_t)((b * NH + h) * 64 + d)) * SEQ + g) = w;
      }
    }
  }
}

// ---------------------------------------------------------------------------
// Output projection: C = At (4096x1024) @ wo^T, fp32 out. 128x128 tiles,
// grid (8,32) = 256 blocks (1/CU, uniform). 2x MFMA per staged byte vs 128x64.
// ---------------------------------------------------------------------------
__launch_bounds__(256, 2)
__global__ void gemm_ao(const unsigned short* __restrict__ A,
                        const unsigned short* __restrict__ B,
                        float* __restrict__ C) {
  __shared__ __align__(16) char smem[32768];

  const int t = threadIdx.x;
  const int lane = t & 63, wave = t >> 6;
  const int quad = lane >> 4, l16 = lane & 15;
  const int m0 = blockIdx.y * 128, n0 = blockIdx.x * 128;
  const int wm = (wave >> 1) * 64, wn = (wave & 1) * 64;

  f32x4 acc[4][4];
#pragma unroll
  for (int i = 0; i < 4; i++)
#pragma unroll
    for (int j = 0; j < 4; j++) { acc[i][j][0]=0.f; acc[i][j][1]=0.f; acc[i][j][2]=0.f; acc[i][j][3]=0.f; }

  const int rr = t >> 2;
  const int cc = (t & 3) * 8;

#define AO_STAGE(bufidx, k0_) do {                                               \
    char* a_ = smem + (bufidx) * 8192;                                            \
    char* b_ = smem + 16384 + (bufidx) * 8192;                                    \
    _Pragma("unroll")                                                             \
    for (int i_ = 0; i_ < 2; i_++) {                                              \
      load_lds16(A + (uint64_t)(m0 + i_ * 64 + rr) * 1024 + (k0_) + cc,           \
                 a_ + i_ * 4096 + wave * 1024);                                   \
      load_lds16(B + (uint64_t)(n0 + i_ * 64 + rr) * 1024 + (k0_) + cc,           \
                 b_ + i_ * 4096 + wave * 1024);                                   \
    }                                                                             \
  } while (0)

  AO_STAGE(0, 0);

  for (int k0 = 0; k0 < 1024; k0 += 32) {
    const int buf = (k0 >> 5) & 1;
    ASM_VMCNT0;
    ASM_BARRIER;
    if (k0 + 32 < 1024) AO_STAGE(buf ^ 1, k0 + 32);
    char* As = smem + buf * 8192;
    char* Bs = smem + 16384 + buf * 8192;

    bf16x8 af[4], bfr[4];
#pragma unroll
    for (int i = 0; i < 4; i++) {
      af[i]  = *(const bf16x8*)(As + (wm + i * 16 + l16) * 64 + quad * 16);
      bfr[i] = *(const bf16x8*)(Bs + (wn + i * 16 + l16) * 64 + quad * 16);
    }
#pragma unroll
    for (int i = 0; i < 4; i++)
#pragma unroll
      for (int j = 0; j < 4; j++)
        acc[i][j] = __builtin_amdgcn_mfma_f32_16x16x32_bf16(af[i], bfr[j], acc[i][j], 0, 0, 0);
  }
#undef AO_STAGE

#pragma unroll
  for (int i = 0; i < 4; i++)
#pragma unroll
    for (int j = 0; j < 4; j++)
#pragma unroll
      for (int r = 0; r < 4; r++) {
        const int m = m0 + wm + i * 16 + quad * 4 + r;
        const int n = n0 + wn + j * 16 + l16;
        C[(uint64_t)m * DM + n] = acc[i][j][r];
      }
}

// ---------------------------------------------------------------------------
// Flash attention r15 = r12 (verified best: flash 42.6us, total 174.2us)
// + T5 s_setprio around the compute region.
// R5 post-mortem: widening per-wave work (32 q-rows) spilled accumulators to
// scratch (4GB phantom traffic, 870us) -- the 16q/wave structure is AT the
// register ceiling; keep it. r12 structure: 1024 blocks x 256 thr (4 waves),
// 4 blocks/CU, one 64-row Q-tile per block, ng=tq+1 K-tiles, big tiles
// launched first. Blocks are independent and sit at different phases ->
// T5's mechanism applies (m191: +4-7% on attn, null only on lockstep GEMM):
// waves inside the MFMA/softmax region run at prio 1 and win CU arbitration
// over waves in the stage/wait region.
// ---------------------------------------------------------------------------
__launch_bounds__(256, 4)
__global__ void flash_attn(const unsigned short* __restrict__ Q,
                           const unsigned short* __restrict__ K,
                           const unsigned short* __restrict__ Vt,
                           unsigned short* __restrict__ Oa) {
  __shared__ __align__(16) char smem[32768];
  // K dbuf: 0 / 8192; V dbuf: 16384 / 24576

  const int t = threadIdx.x;
  const int lane = t & 63, wid = t >> 6;     // wid = 0..3
  const int quad = lane >> 4, l16 = lane & 15;
  const int u = blockIdx.x;
  const int tq = 31 - (u >> 5);              // Q-tile index, big tiles first
  const int bh = u & 31;
  const uint64_t base = (uint64_t)bh * (SEQ * 64);
  const int qb = tq * 64;
  const int ng = tq + 1;                     // K-tiles for this Q-tile
  const int qg = qb + wid * 16 + l16;        // this lane's q row
  const int b = bh >> 4, h = bh & 15;

  // Q B-fragment (n=q=l16, k=d=kk*32+quad*8+j)
  bf16x8 qf[2];
  {
    const unsigned short* qp = Q + base + (uint64_t)qg * 64 + quad * 8;
    qf[0] = *(const bf16x8*)qp;  qf[1] = *(const bf16x8*)(qp + 32);
  }

  f32x4 o[4];
#pragma unroll
  for (int i = 0; i < 4; i++) { o[i][0]=0.f; o[i][1]=0.f; o[i][2]=0.f; o[i][3]=0.f; }
  float lI = 0.f;

  // staging: 256 threads cover a 64-row x 128B tile in 2 calls/array.
  // LDS chunk c at row r holds global 16B-chunk c ^ (r&7).
  // row r = wid*16 + i*8 + (lane>>3); r&7 = lane>>3 (i*8 only sets bit 3).
  const int sr8 = lane >> 3;
  const int sc = ((lane & 7) ^ sr8) * 8;     // shorts
  const int swz = (l16 & 7);

#define STAGE(bufidx, kb_) do {                                                   \
    _Pragma("unroll")                                                             \
    for (int i_ = 0; i_ < 2; i_++) {                                              \
      const int r_ = wid * 16 + i_ * 8 + sr8;                                     \
      load_lds16(K  + base + (uint64_t)((kb_) + r_) * 64 + sc,                    \
                 smem + (bufidx) * 8192 + wid * 2048 + i_ * 1024);                \
      load_lds16(Vt + base + (uint64_t)r_ * SEQ + (kb_) + sc,                     \
                 smem + 16384 + (bufidx) * 8192 + wid * 2048 + i_ * 1024);        \
    }                                                                             \
  } while (0)

  STAGE(0, 0);

  const float c1 = 0.18033688011f;  // log2(e)/8

  for (int it = 0; it < ng; it++) {
    const int kb = it * 64;
    const int buf = it & 1;
    ASM_VMCNT0;     // stage(it) loads were issued a full iteration ago
    ASM_BARRIER;
    if (it + 1 < ng) STAGE(buf ^ 1, (it + 1) * 64);
    char* ks = smem + buf * 8192;
    char* vs = smem + 16384 + buf * 8192;

    int nbmax = ((qb + wid * 16 + 15 - kb) >> 4) + 1;
    nbmax = nbmax > 4 ? 4 : (nbmax < 0 ? 0 : nbmax);
    const bool diag = (kb + 63) > (qb + wid * 16);   // wave-uniform

    // S^T = K Q^T : key = kb + nb*16 + quad*4 + r, q = l16
    __builtin_amdgcn_s_setprio(1);
    f32x4 sf[4];
    float ls = 0.f;
#pragma unroll
    for (int nb = 0; nb < 4; nb++) {
      if (nb < nbmax) {
        f32x4 s; s[0]=0.f; s[1]=0.f; s[2]=0.f; s[3]=0.f;
#pragma unroll
        for (int kk = 0; kk < 2; kk++) {
          bf16x8 kfr = *(const bf16x8*)(ks + (nb * 16 + l16) * 128 + (((kk * 4 + quad) ^ swz) * 16));
          s = __builtin_amdgcn_mfma_f32_16x16x32_bf16(kfr, qf[kk], s, 0, 0, 0);
        }
        if (diag) {
#pragma unroll
          for (int r = 0; r < 4; r++) {
            const int key = kb + nb * 16 + quad * 4 + r;
            const float p = (key <= qg) ? __builtin_amdgcn_exp2f(s[r] * c1) : 0.f;
            sf[nb][r] = p;  ls += p;
          }
        } else {
#pragma unroll
          for (int r = 0; r < 4; r++) {
            const float p = __builtin_amdgcn_exp2f(s[r] * c1);
            sf[nb][r] = p;  ls += p;
          }
        }
      }
    }
    lI += ls;   // lane-local partial (this quad's keys); reduced at epilogue

    // PV: P in regs; V-frag pair (nb=2np, 2np+1) in ONE b128 from permuted V.
#pragma unroll
    for (int np = 0; np < 2; np++) {
      if (2 * np < nbmax) {
        union { uint2 u; s16x4 h; } p0;
        p0.u.x = pk2(sf[2 * np][0], sf[2 * np][1]);
        p0.u.y = pk2(sf[2 * np][2], sf[2 * np][3]);
        const bool hi = (2 * np + 1 < nbmax);
        union { uint2 u; s16x4 h; } p1;
        if (hi) {
          p1.u.x = pk2(sf[2 * np + 1][0], sf[2 * np + 1][1]);
          p1.u.y = pk2(sf[2 * np + 1][2], sf[2 * np + 1][3]);
        }
#pragma unroll
        for (int db = 0; db < 4; db++) {
          s16x8 vv = *(const s16x8*)(vs + (db * 16 + l16) * 128 +
                                     (((quad * 2 + np) ^ swz) * 16));
          s16x4 vlo = __builtin_shufflevector(vv, vv, 0, 1, 2, 3);
          o[db] = __builtin_amdgcn_mfma_f32_16x16x16bf16_1k(vlo, p0.h, o[db], 0, 0, 0);
          if (hi) {
            s16x4 vhi = __builtin_shufflevector(vv, vv, 4, 5, 6, 7);
            o[db] = __builtin_amdgcn_mfma_f32_16x16x16bf16_1k(vhi, p1.h, o[db], 0, 0, 0);
          }
        }
      }
    }
    __builtin_amdgcn_s_setprio(0);
  }
#undef STAGE

  // epilogue: reduce l across quads, normalize, store
  float lr = lI;
  lr += __shfl_xor(lr, 16);
  lr += __shfl_xor(lr, 32);
  const float invl = 1.0f / lr;
  unsigned short* orow = Oa + ((uint64_t)(b * SEQ + qg)) * DM + h * 64 + quad * 4;
#pragma unroll
  for (int db = 0; db < 4; db++) {
    uint2 w;
    w.x = pk2(o[db][0] * invl, o[db][1] * invl);
    w.y = pk2(o[db][2] * invl, o[db][3] * invl);
    *(uint2*)(orow + db * 16) = w;
  }
}

extern "C" void kernel_launch(void* const* d_in, const int* in_sizes, int n_in,
                              void* d_out, int out_size, void* d_ws, size_t ws_size,
                              hipStream_t stream) {
  const float* x  = (const float*)d_in[0];
  const int* tp   = (const int*)d_in[1];
  const float* wq = (const float*)d_in[2];
  const float* wk = (const float*)d_in[3];
  const float* wv = (const float*)d_in[4];
  const float* wo = (const float*)d_in[5];
  float* out = (float*)d_out;

  unsigned short* ws = (unsigned short*)d_ws;
  unsigned short* xb  = ws;                   // (b,s,dm) bf16        8 MB
  unsigned short* w3b = ws + 4194304;         // [wq;wk;wv] 3072x1024 6 MB
  unsigned short* wob = ws + 7340032;         // 2 MB
  unsigned short* Qr  = ws + 8388608;         // (b,h,s,64)  8 MB
  unsigned short* Kr  = ws + 12582912;        // (b,h,s,64)  8 MB
  unsigned short* Vt  = ws + 16777216;        // (b,h,64,s-perm)  8 MB
  unsigned short* At  = ws + 20971520;        // (b,s,h*64)  8 MB

  cvt_all<<<8192, 256, 0, stream>>>(x, wq, wk, wv, wo, ws);
  gemm_qkv<<<dim3(24, 32), 256, 0, stream>>>(xb, w3b, Qr, Kr, Vt, tp);
  flash_attn<<<1024, 256, 0, stream>>>(Qr, Kr, Vt, At);
  gemm_ao<<<dim3(8, 32), 256, 0, stream>>>(At, wob, out);
}

// Round 7
// 171.365 us; speedup vs baseline: 6.0747x; 1.0139x over previous
//
#include <hip/hip_runtime.h>
#include <stdint.h>
#include <math.h>

#define SEQ 2048
#define NH 16
#define DM 1024

typedef __bf16 bf16x8 __attribute__((ext_vector_type(8)));
typedef __bf16 bf16x2 __attribute__((ext_vector_type(2)));
typedef short s16x4 __attribute__((ext_vector_type(4)));
typedef short s16x8 __attribute__((ext_vector_type(8)));
typedef float f32x4 __attribute__((ext_vector_type(4)));
typedef float f32x2 __attribute__((ext_vector_type(2)));

#define ASM_VMCNT0  asm volatile("s_waitcnt vmcnt(0)" ::: "memory")
#define ASM_BARRIER asm volatile("s_barrier" ::: "memory")

__device__ __forceinline__ unsigned short f2bf(float f) {
  union { float f; unsigned u; } v; v.f = f;
  unsigned r = v.u + 0x7fffu + ((v.u >> 16) & 1u);
  return (unsigned short)(r >> 16);
}
__device__ __forceinline__ unsigned pk2(float a, float b) {
  f32x2 v = {a, b};
  bf16x2 r = __builtin_convertvector(v, bf16x2);  // v_cvt_pk_bf16_f32
  union { bf16x2 h; unsigned u; } c; c.h = r;
  return c.u;
}
__device__ __forceinline__ void load_lds16(const void* g, void* l) {
  __builtin_amdgcn_global_load_lds((__attribute__((address_space(1))) void*)g,
                                   (__attribute__((address_space(3))) void*)l,
                                   16, 0, 0);
}

// ---------------------------------------------------------------------------
// fp32 -> bf16 conversion: x (4M) + wq/wk/wv/wo (1M each) into ws.
// ---------------------------------------------------------------------------
__global__ void cvt_all(const float* __restrict__ x, const float* __restrict__ wq,
                        const float* __restrict__ wk, const float* __restrict__ wv,
                        const float* __restrict__ wo, unsigned short* __restrict__ ws) {
  const int i = blockIdx.x * blockDim.x + threadIdx.x;
  const int off = i * 4;
  const float* src;
  unsigned short* dst;
  if (off < 4194304) {
    src = x + off;  dst = ws + off;
  } else {
    const int r = off - 4194304;
    const int w = r >> 20, o = r & 1048575;
    const float* tabs[4] = {wq, wk, wv, wo};
    src = tabs[w] + o;  dst = ws + 4194304 + (w << 20) + o;
  }
  const float4 v = *(const float4*)src;
  uint2 u;
  u.x = pk2(v.x, v.y);
  u.y = pk2(v.z, v.w);
  *(uint2*)dst = u;
}

// ---------------------------------------------------------------------------
// Fused QKV projection: C = x (4096x1024) @ W3^T (W3 = [wq;wk;wv], 3072x1024).
// 128x128 tiles, grid (24,32) = 768 blocks; 3 blocks/CU.
// V epilogue writes the key dim PERMUTED within each 64-block:
//   key = nb*16 + quad*4 + j  ->  g = quad*16 + (nb>>1)*8 + (nb&1)*4 + j
// so flash PV A-fragments (4 keys/lane, 2 nb per 16B) are b128-loadable.
// ---------------------------------------------------------------------------
__launch_bounds__(256, 3)
__global__ void gemm_qkv(const unsigned short* __restrict__ X,
                         const unsigned short* __restrict__ W3,
                         unsigned short* __restrict__ Qr,
                         unsigned short* __restrict__ Kr,
                         unsigned short* __restrict__ Vt,
                         const int* __restrict__ tp) {
  __shared__ __align__(16) char smem[32768];

  const int t = threadIdx.x;
  const int lane = t & 63, wave = t >> 6;
  const int quad = lane >> 4, l16 = lane & 15;
  const int m0 = blockIdx.y * 128, n0 = blockIdx.x * 128;
  const int wm = (wave >> 1) * 64, wn = (wave & 1) * 64;

  f32x4 acc[4][4];
#pragma unroll
  for (int i = 0; i < 4; i++)
#pragma unroll
    for (int j = 0; j < 4; j++) { acc[i][j][0]=0.f; acc[i][j][1]=0.f; acc[i][j][2]=0.f; acc[i][j][3]=0.f; }

  const int rr = t >> 2;
  const int cc = (t & 3) * 8;

#define QKV_STAGE(bufidx, k0_) do {                                               \
    char* a_ = smem + (bufidx) * 8192;                                            \
    char* b_ = smem + 16384 + (bufidx) * 8192;                                    \
    _Pragma("unroll")                                                             \
    for (int i_ = 0; i_ < 2; i_++) {                                              \
      load_lds16(X  + (uint64_t)(m0 + i_ * 64 + rr) * 1024 + (k0_) + cc,          \
                 a_ + i_ * 4096 + wave * 1024);                                   \
      load_lds16(W3 + (uint64_t)(n0 + i_ * 64 + rr) * 1024 + (k0_) + cc,          \
                 b_ + i_ * 4096 + wave * 1024);                                   \
    }                                                                             \
  } while (0)

  QKV_STAGE(0, 0);

  for (int k0 = 0; k0 < 1024; k0 += 32) {
    const int buf = (k0 >> 5) & 1;
    ASM_VMCNT0;
    ASM_BARRIER;
    if (k0 + 32 < 1024) QKV_STAGE(buf ^ 1, k0 + 32);
    char* As = smem + buf * 8192;
    char* Bs = smem + 16384 + buf * 8192;

    bf16x8 af[4], bfr[4];
#pragma unroll
    for (int i = 0; i < 4; i++) {
      af[i]  = *(const bf16x8*)(As + (wm + i * 16 + l16) * 64 + quad * 16);
      bfr[i] = *(const bf16x8*)(Bs + (wn + i * 16 + l16) * 64 + quad * 16);
    }
#pragma unroll
    for (int i = 0; i < 4; i++)
#pragma unroll
      for (int j = 0; j < 4; j++)
        acc[i][j] = __builtin_amdgcn_mfma_f32_16x16x32_bf16(af[i], bfr[j], acc[i][j], 0, 0, 0);
  }
#undef QKV_STAGE

  if (n0 < 2048) {
    unsigned short* dst = (n0 < 1024) ? Qr : Kr;
    float fr[4]; int dd[4], hh[4];
#pragma unroll
    for (int j = 0; j < 4; j++) {
      const int n = n0 + wn + j * 16 + l16;
      dd[j] = n & 63;
      hh[j] = (n & 1023) >> 6;
      fr[j] = __builtin_amdgcn_exp2f(-0.20762050594f * (float)(dd[j] & ~1)) * 0.15915494309f;
    }
    const float sgnodd = (l16 & 1) ? 1.f : -1.f;
#pragma unroll
    for (int i = 0; i < 4; i++) {
#pragma unroll
      for (int r = 0; r < 4; r++) {
        const int m = m0 + wm + i * 16 + quad * 4 + r;
        const int s = m & 2047, b = m >> 11;
        const float posf = (float)tp[m];
#pragma unroll
        for (int j = 0; j < 4; j++) {
          const float v = acc[i][j][r];
          const float p = __shfl_xor(v, 1);
          float rev = posf * fr[j];
          rev -= floorf(rev);
          float sn, cs;
          asm("v_sin_f32 %0, %1" : "=v"(sn) : "v"(rev));
          asm("v_cos_f32 %0, %1" : "=v"(cs) : "v"(rev));
          const float rv = fmaf(v, cs, p * sn * sgnodd);
          dst[((uint64_t)((b * NH + hh[j]) * SEQ + s)) * 64 + dd[j]] = f2bf(rv);
        }
      }
    }
  } else {
    // V -> Vt (b,h,d,s_permuted): 4 consecutive s (=j) share (quad_v, nb_v).
#pragma unroll
    for (int i = 0; i < 4; i++) {
      const int m = m0 + wm + i * 16 + quad * 4;
      const int s = m & 2047, b = m >> 11;
      const int sl = s & 63;
      const int qv = (sl >> 2) & 3, nv = sl >> 4;
      const int g = (s & ~63) + qv * 16 + (nv >> 1) * 8 + (nv & 1) * 4;
#pragma unroll
      for (int j = 0; j < 4; j++) {
        const int n = n0 - 2048 + wn + j * 16 + l16;
        const int h = n >> 6, d = n & 63;
        uint2 w;
        w.x = pk2(acc[i][j][0], acc[i][j][1]);
        w.y = pk2(acc[i][j][2], acc[i][j][3]);
        *(uint2*)(Vt + ((uint64_t)((b * NH + h) * 64 + d)) * SEQ + g) = w;
      }
    }
  }
}

// ---------------------------------------------------------------------------
// Output projection: C = At (4096x1024) @ wo^T, fp32 out. 128x128 tiles,
// grid (8,32) = 256 blocks (1/CU). r16: XCD-GROUPED block remap -- default
// linear dispatch puts the 8 n-blocks of one A row-strip on 8 DIFFERENT XCDs
// (id%8 = n-strip), so each A strip is re-fetched 8x through L3. Remap so
// XCD k (= id%8) owns m-strips {4k..4k+3} x all 8 n-strips: per-XCD working
// set = 1MB A + 2MB wo = 3MB <= 4MB L2 -> A/wo re-reads become L2 hits.
// Bijective: (id&7, id>>3) -> m0=(k*4 + t%4), n0=t/4.
// ---------------------------------------------------------------------------
__launch_bounds__(256, 2)
__global__ void gemm_ao(const unsigned short* __restrict__ A,
                        const unsigned short* __restrict__ B,
                        float* __restrict__ C) {
  __shared__ __align__(16) char smem[32768];

  const int t = threadIdx.x;
  const int lane = t & 63, wave = t >> 6;
  const int quad = lane >> 4, l16 = lane & 15;
  const int id = blockIdx.y * 8 + blockIdx.x;   // linear dispatch id, 0..255
  const int k = id & 7;                         // XCD (1 block/CU round-robin)
  const int tt = id >> 3;                       // 0..31
  const int m0 = (k * 4 + (tt & 3)) * 128;      // XCD k: m-strips 4k..4k+3
  const int n0 = (tt >> 2) * 128;               // all 8 n-strips
  const int wm = (wave >> 1) * 64, wn = (wave & 1) * 64;

  f32x4 acc[4][4];
#pragma unroll
  for (int i = 0; i < 4; i++)
#pragma unroll
    for (int j = 0; j < 4; j++) { acc[i][j][0]=0.f; acc[i][j][1]=0.f; acc[i][j][2]=0.f; acc[i][j][3]=0.f; }

  const int rr = t >> 2;
  const int cc = (t & 3) * 8;

#define AO_STAGE(bufidx, k0_) do {                                               \
    char* a_ = smem + (bufidx) * 8192;                                            \
    char* b_ = smem + 16384 + (bufidx) * 8192;                                    \
    _Pragma("unroll")                                                             \
    for (int i_ = 0; i_ < 2; i_++) {                                              \
      load_lds16(A + (uint64_t)(m0 + i_ * 64 + rr) * 1024 + (k0_) + cc,           \
                 a_ + i_ * 4096 + wave * 1024);                                   \
      load_lds16(B + (uint64_t)(n0 + i_ * 64 + rr) * 1024 + (k0_) + cc,           \
                 b_ + i_ * 4096 + wave * 1024);                                   \
    }                                                                             \
  } while (0)

  AO_STAGE(0, 0);

  for (int k0 = 0; k0 < 1024; k0 += 32) {
    const int buf = (k0 >> 5) & 1;
    ASM_VMCNT0;
    ASM_BARRIER;
    if (k0 + 32 < 1024) AO_STAGE(buf ^ 1, k0 + 32);
    char* As = smem + buf * 8192;
    char* Bs = smem + 16384 + buf * 8192;

    bf16x8 af[4], bfr[4];
#pragma unroll
    for (int i = 0; i < 4; i++) {
      af[i]  = *(const bf16x8*)(As + (wm + i * 16 + l16) * 64 + quad * 16);
      bfr[i] = *(const bf16x8*)(Bs + (wn + i * 16 + l16) * 64 + quad * 16);
    }
#pragma unroll
    for (int i = 0; i < 4; i++)
#pragma unroll
      for (int j = 0; j < 4; j++)
        acc[i][j] = __builtin_amdgcn_mfma_f32_16x16x32_bf16(af[i], bfr[j], acc[i][j], 0, 0, 0);
  }
#undef AO_STAGE

#pragma unroll
  for (int i = 0; i < 4; i++)
#pragma unroll
    for (int j = 0; j < 4; j++)
#pragma unroll
      for (int r = 0; r < 4; r++) {
        const int m = m0 + wm + i * 16 + quad * 4 + r;
        const int n = n0 + wn + j * 16 + l16;
        C[(uint64_t)m * DM + n] = acc[i][j][r];
      }
}

// ---------------------------------------------------------------------------
// Flash attention r16 = r12 exactly (verified best: flash 42.6us).
// R6 A/B: setprio(1) around compute HURT flash +3.5us (4-wave lockstep blocks
// -- boosting compute waves starves other blocks' staging waves; m191's win
// was on 1-wave blocks). Removed. Structure: 1024 blocks x 256 thr (4 waves),
// 4 blocks/CU, one 64-row Q-tile per block, ng=tq+1 K-tiles, big tiles first.
// ---------------------------------------------------------------------------
__launch_bounds__(256, 4)
__global__ void flash_attn(const unsigned short* __restrict__ Q,
                           const unsigned short* __restrict__ K,
                           const unsigned short* __restrict__ Vt,
                           unsigned short* __restrict__ Oa) {
  __shared__ __align__(16) char smem[32768];
  // K dbuf: 0 / 8192; V dbuf: 16384 / 24576

  const int t = threadIdx.x;
  const int lane = t & 63, wid = t >> 6;     // wid = 0..3
  const int quad = lane >> 4, l16 = lane & 15;
  const int u = blockIdx.x;
  const int tq = 31 - (u >> 5);              // Q-tile index, big tiles first
  const int bh = u & 31;
  const uint64_t base = (uint64_t)bh * (SEQ * 64);
  const int qb = tq * 64;
  const int ng = tq + 1;                     // K-tiles for this Q-tile
  const int qg = qb + wid * 16 + l16;        // this lane's q row
  const int b = bh >> 4, h = bh & 15;

  // Q B-fragment (n=q=l16, k=d=kk*32+quad*8+j)
  bf16x8 qf[2];
  {
    const unsigned short* qp = Q + base + (uint64_t)qg * 64 + quad * 8;
    qf[0] = *(const bf16x8*)qp;  qf[1] = *(const bf16x8*)(qp + 32);
  }

  f32x4 o[4];
#pragma unroll
  for (int i = 0; i < 4; i++) { o[i][0]=0.f; o[i][1]=0.f; o[i][2]=0.f; o[i][3]=0.f; }
  float lI = 0.f;

  // staging: 256 threads cover a 64-row x 128B tile in 2 calls/array.
  // LDS chunk c at row r holds global 16B-chunk c ^ (r&7).
  // row r = wid*16 + i*8 + (lane>>3); r&7 = lane>>3 (i*8 only sets bit 3).
  const int sr8 = lane >> 3;
  const int sc = ((lane & 7) ^ sr8) * 8;     // shorts
  const int swz = (l16 & 7);

#define STAGE(bufidx, kb_) do {                                                   \
    _Pragma("unroll")                                                             \
    for (int i_ = 0; i_ < 2; i_++) {                                              \
      const int r_ = wid * 16 + i_ * 8 + sr8;                                     \
      load_lds16(K  + base + (uint64_t)((kb_) + r_) * 64 + sc,                    \
                 smem + (bufidx) * 8192 + wid * 2048 + i_ * 1024);                \
      load_lds16(Vt + base + (uint64_t)r_ * SEQ + (kb_) + sc,                     \
                 smem + 16384 + (bufidx) * 8192 + wid * 2048 + i_ * 1024);        \
    }                                                                             \
  } while (0)

  STAGE(0, 0);

  const float c1 = 0.18033688011f;  // log2(e)/8

  for (int it = 0; it < ng; it++) {
    const int kb = it * 64;
    const int buf = it & 1;
    ASM_VMCNT0;     // stage(it) loads were issued a full iteration ago
    ASM_BARRIER;
    if (it + 1 < ng) STAGE(buf ^ 1, (it + 1) * 64);
    char* ks = smem + buf * 8192;
    char* vs = smem + 16384 + buf * 8192;

    int nbmax = ((qb + wid * 16 + 15 - kb) >> 4) + 1;
    nbmax = nbmax > 4 ? 4 : (nbmax < 0 ? 0 : nbmax);
    const bool diag = (kb + 63) > (qb + wid * 16);   // wave-uniform

    // S^T = K Q^T : key = kb + nb*16 + quad*4 + r, q = l16
    f32x4 sf[4];
    float ls = 0.f;
#pragma unroll
    for (int nb = 0; nb < 4; nb++) {
      if (nb < nbmax) {
        f32x4 s; s[0]=0.f; s[1]=0.f; s[2]=0.f; s[3]=0.f;
#pragma unroll
        for (int kk = 0; kk < 2; kk++) {
          bf16x8 kfr = *(const bf16x8*)(ks + (nb * 16 + l16) * 128 + (((kk * 4 + quad) ^ swz) * 16));
          s = __builtin_amdgcn_mfma_f32_16x16x32_bf16(kfr, qf[kk], s, 0, 0, 0);
        }
        if (diag) {
#pragma unroll
          for (int r = 0; r < 4; r++) {
            const int key = kb + nb * 16 + quad * 4 + r;
            const float p = (key <= qg) ? __builtin_amdgcn_exp2f(s[r] * c1) : 0.f;
            sf[nb][r] = p;  ls += p;
          }
        } else {
#pragma unroll
          for (int r = 0; r < 4; r++) {
            const float p = __builtin_amdgcn_exp2f(s[r] * c1);
            sf[nb][r] = p;  ls += p;
          }
        }
      }
    }
    lI += ls;   // lane-local partial (this quad's keys); reduced at epilogue

    // PV: P in regs; V-frag pair (nb=2np, 2np+1) in ONE b128 from permuted V.
#pragma unroll
    for (int np = 0; np < 2; np++) {
      if (2 * np < nbmax) {
        union { uint2 u; s16x4 h; } p0;
        p0.u.x = pk2(sf[2 * np][0], sf[2 * np][1]);
        p0.u.y = pk2(sf[2 * np][2], sf[2 * np][3]);
        const bool hi = (2 * np + 1 < nbmax);
        union { uint2 u; s16x4 h; } p1;
        if (hi) {
          p1.u.x = pk2(sf[2 * np + 1][0], sf[2 * np + 1][1]);
          p1.u.y = pk2(sf[2 * np + 1][2], sf[2 * np + 1][3]);
        }
#pragma unroll
        for (int db = 0; db < 4; db++) {
          s16x8 vv = *(const s16x8*)(vs + (db * 16 + l16) * 128 +
                                     (((quad * 2 + np) ^ swz) * 16));
          s16x4 vlo = __builtin_shufflevector(vv, vv, 0, 1, 2, 3);
          o[db] = __builtin_amdgcn_mfma_f32_16x16x16bf16_1k(vlo, p0.h, o[db], 0, 0, 0);
          if (hi) {
            s16x4 vhi = __builtin_shufflevector(vv, vv, 4, 5, 6, 7);
            o[db] = __builtin_amdgcn_mfma_f32_16x16x16bf16_1k(vhi, p1.h, o[db], 0, 0, 0);
          }
        }
      }
    }
  }
#undef STAGE

  // epilogue: reduce l across quads, normalize, store
  float lr = lI;
  lr += __shfl_xor(lr, 16);
  lr += __shfl_xor(lr, 32);
  const float invl = 1.0f / lr;
  unsigned short* orow = Oa + ((uint64_t)(b * SEQ + qg)) * DM + h * 64 + quad * 4;
#pragma unroll
  for (int db = 0; db < 4; db++) {
    uint2 w;
    w.x = pk2(o[db][0] * invl, o[db][1] * invl);
    w.y = pk2(o[db][2] * invl, o[db][3] * invl);
    *(uint2*)(orow + db * 16) = w;
  }
}

extern "C" void kernel_launch(void* const* d_in, const int* in_sizes, int n_in,
                              void* d_out, int out_size, void* d_ws, size_t ws_size,
                              hipStream_t stream) {
  const float* x  = (const float*)d_in[0];
  const int* tp   = (const int*)d_in[1];
  const float* wq = (const float*)d_in[2];
  const float* wk = (const float*)d_in[3];
  const float* wv = (const float*)d_in[4];
  const float* wo = (const float*)d_in[5];
  float* out = (float*)d_out;

  unsigned short* ws = (unsigned short*)d_ws;
  unsigned short* xb  = ws;                   // (b,s,dm) bf16        8 MB
  unsigned short* w3b = ws + 4194304;         // [wq;wk;wv] 3072x1024 6 MB
  unsigned short* wob = ws + 7340032;         // 2 MB
  unsigned short* Qr  = ws + 8388608;         // (b,h,s,64)  8 MB
  unsigned short* Kr  = ws + 12582912;        // (b,h,s,64)  8 MB
  unsigned short* Vt  = ws + 16777216;        // (b,h,64,s-perm)  8 MB
  unsigned short* At  = ws + 20971520;        // (b,s,h*64)  8 MB

  cvt_all<<<8192, 256, 0, stream>>>(x, wq, wk, wv, wo, ws);
  gemm_qkv<<<dim3(24, 32), 256, 0, stream>>>(xb, w3b, Qr, Kr, Vt, tp);
  flash_attn<<<1024, 256, 0, stream>>>(Qr, Kr, Vt, At);
  gemm_ao<<<dim3(8, 32), 256, 0, stream>>>(At, wob, out);
}